// Round 7
// baseline (236.857 us; speedup 1.0000x reference)
//
#include <hip/hip_runtime.h>
#include <hip/hip_bf16.h>

#define B_SZ 16384
#define F_SZ 2048
#define D_SZ 256
#define E_SZ 8
#define GRID_G 184   // >= max tiles (sum_e ceil(count_e/96) <= 178); 184 = 8*23
#define XCHUNK (GRID_G / 8)

typedef __attribute__((ext_vector_type(8))) short bhalf8;
typedef __attribute__((ext_vector_type(4))) float fl4;

__device__ __forceinline__ short f2b(float f) {
  __hip_bfloat16 h = __float2bfloat16(f);
  union { __hip_bfloat16 h; short s; } u;
  u.h = h;
  return u.s;
}

// ---------------- bucket scatter ----------------
__global__ void k_scatter(const int* __restrict__ ids, int* __restrict__ counts,
                          int* __restrict__ perm) {
  __shared__ int lcnt[E_SZ], lbase[E_SZ];
  int t = threadIdx.x;
  if (t < E_SZ) lcnt[t] = 0;
  __syncthreads();
  int b = blockIdx.x * 256 + t;
  int e = ids[b];
  int p = atomicAdd(&lcnt[e], 1);
  __syncthreads();
  if (t < E_SZ) lbase[t] = atomicAdd(&counts[t], lcnt[t]);
  __syncthreads();
  perm[e * B_SZ + lbase[e] + p] = b;
}

// ---------------- W transpose+cast: Wt[e][d][f] = bf16(W[e][f][d]) ----------------
__global__ void k_transpose(const float* __restrict__ W, __hip_bfloat16* __restrict__ Wt) {
  __shared__ float tile[64][65];
  int e = blockIdx.z;
  int f0 = blockIdx.x * 64;
  int d0 = blockIdx.y * 64;
  int t = threadIdx.x;
  const float* src = W + ((size_t)e * F_SZ + f0) * D_SZ + d0;
  int fr = t >> 2, c0 = t & 3;
#pragma unroll
  for (int c = c0; c < 16; c += 4) {
    float4 v = *(const float4*)(src + (size_t)fr * D_SZ + c * 4);
    tile[fr][c * 4 + 0] = v.x;
    tile[fr][c * 4 + 1] = v.y;
    tile[fr][c * 4 + 2] = v.z;
    tile[fr][c * 4 + 3] = v.w;
  }
  __syncthreads();
  int dr = t >> 2, cc = t & 3;
  union { unsigned short u[16]; bhalf8 v[2]; } pk;
#pragma unroll
  for (int k = 0; k < 16; ++k) pk.u[k] = (unsigned short)f2b(tile[cc * 16 + k][dr]);
  __hip_bfloat16* dst = Wt + ((size_t)e * D_SZ + d0 + dr) * F_SZ + f0 + cc * 16;
  ((bhalf8*)dst)[0] = pk.v[0];
  ((bhalf8*)dst)[1] = pk.v[1];
}

// ---------------- async 16B global -> LDS ----------------
__device__ __forceinline__ void load_lds16(const __hip_bfloat16* g, __hip_bfloat16* l) {
  __builtin_amdgcn_global_load_lds((const __attribute__((address_space(1))) void*)g,
                                   (__attribute__((address_space(3))) void*)l, 16, 0, 0);
}

// ---------------- gather GEMM: BM=96, BN=256, BK=64, deep-pipelined ----------------
// [R6 fix: tail tile 31 must read Bs[31%3 = 1] (offset 16384), not Bs[2].
//  B(j) lives in buffer j%3; R6 read B(29)'s buffer for the last K-slice ->
//  absmax 1.30 (matches 5-sigma of one 64-wide K-slice difference). Full vmcnt
//  ledger + WAR hazard audit otherwise clean.]
// R5 lesson: per-CU delivery rate tracks outstanding-load pressure (R4 straggler
// CU w/ 16 waves: 14.1 B/cyc; R5 w/ 8 waves + shallow queue: 10.2). This round:
// B prefetch distance 2 via TRIPLE-buffered Bs. B(kk+2) issued iter kk, drained
// end of iter kk+1 -> one full iteration (~4000 cyc) of latency cover; steady
// in-flight across barrier = 10 loads/wave (B(k+2)x4 + A(k+2)x3 + A(k+3)x3).
// End-of-iter s_waitcnt vmcnt(10) drains exactly B(kk+1).
// Main loop unrolled x6 (lcm of A-parity 2 and B-mod 3) so all buffer indices
// are compile-time literals.
// 8 waves (2m x 4n), wave tile 48x64: acc[3][4], 24 MFMA/wave/iter.
// LDS: As 2x96x64x2B = 24KB, Bs 3x256x64x2B = 96KB -> 120KB (1 block/CU; fine,
// blocks(<=178) < CUs(256)). Rows 64 elems (128B), 16B chunk c at (c^(row&7))
// -> ds_read_b128 fragment reads 2-way aliased (free).
__launch_bounds__(512, 2)
__global__ void k_gemm(const float* __restrict__ x, const __hip_bfloat16* __restrict__ Wt,
                       const float* __restrict__ bias, const int* __restrict__ counts,
                       const int* __restrict__ perm, float* __restrict__ out) {
  // XCD-aware remap (184 = 8*23, bijective); experts cluster per XCD L2
  int bid = blockIdx.x;
  int mt = (bid & 7) * XCHUNK + (bid >> 3);
  int e = -1, mbase = 0, count = 0;
  {
    int acc0 = 0;
#pragma unroll
    for (int ee = 0; ee < E_SZ; ++ee) {
      int c = counts[ee];
      int nt = (c + 95) / 96;
      if (e < 0 && mt < acc0 + nt) { e = ee; mbase = (mt - acc0) * 96; count = c; }
      acc0 += nt;
    }
  }
  if (e < 0) return;

  __shared__ __align__(16) __hip_bfloat16 As[2 * 96 * 64];     // 24 KB (2 bufs)
  __shared__ __align__(16) __hip_bfloat16 Bs[3 * 256 * 64];    // 96 KB (3 bufs)

  int t = threadIdx.x;
  int w = t >> 6;
  int lane = t & 63;
  int wm = w >> 2, wn = w & 3;
  int l15 = lane & 15;
  int q = lane >> 4;

  const int* permE = perm + e * B_SZ;

  // ---- A staging: float4 index = i*512+t -> row i*32+(t>>4), k-chunk (t&15) ----
  int tr = t >> 4;      // 0..31
  int tc = t & 15;      // float4 index within row
  const float* pA[3];
  int wAo[3];           // As element offset (within buffer) for ds_write (8B each)
#pragma unroll
  for (int i = 0; i < 3; ++i) {
    int r = i * 32 + tr;                 // 0..95
    int gm = mbase + r;
    int src = permE[(gm < count) ? gm : mbase];
    pA[i] = x + (size_t)src * F_SZ + tc * 4;
    int cw = tc >> 1, half = tc & 1;
    wAo[i] = r * 64 + ((cw ^ (r & 7)) * 8) + half * 4;
  }

  // ---- B staging: physical 16B chunk p = i*512+t; n=p>>3; logical chunk=(p&7)^(n&7) ----
  const __hip_bfloat16* pB[4];
  int dB[4];            // wave-uniform LDS elem offset within a buffer (HW adds lane*16B)
#pragma unroll
  for (int i = 0; i < 4; ++i) {
    int p = i * 512 + t;
    int n = p >> 3;                  // 0..255
    int cl = (p & 7) ^ (n & 7);
    pB[i] = Wt + (size_t)(e * D_SZ + n) * F_SZ + cl * 8;
    dB[i] = i * 4096 + w * 512;
  }

  // fragment read offsets (element units, within buffer)
  int rAo[2][3], rBo[2][4];
#pragma unroll
  for (int ks = 0; ks < 2; ++ks) {
#pragma unroll
    for (int i = 0; i < 3; ++i) {
      int m = wm * 48 + i * 16 + l15;    // 0..95
      rAo[ks][i] = m * 64 + (((ks * 4 + q) ^ (m & 7)) * 8);
    }
#pragma unroll
    for (int j = 0; j < 4; ++j) {
      int n = wn * 64 + j * 16 + l15;
      rBo[ks][j] = n * 64 + (((ks * 4 + q) ^ (n & 7)) * 8);
    }
  }

  fl4 zz = {0.0f, 0.0f, 0.0f, 0.0f};
  fl4 acc[3][4];
#pragma unroll
  for (int i = 0; i < 3; ++i)
#pragma unroll
    for (int j = 0; j < 4; ++j) acc[i][j] = zz;

  float4 avA[3], avB[3];

  // ---------------- prologue: B(0)->buf0, B(1)->buf1, A(0)->As0, A(1)/A(2) in regs ----
#pragma unroll
  for (int i = 0; i < 4; ++i) load_lds16(pB[i], Bs + dB[i]);
#pragma unroll
  for (int i = 0; i < 4; ++i) load_lds16(pB[i] + 64, Bs + 16384 + dB[i]);
  __builtin_amdgcn_sched_barrier(0);
  {
    float4 avP[3];
#pragma unroll
    for (int i = 0; i < 3; ++i) avP[i] = *(const float4*)(pA[i]);
    // auto-wait for avP drains B(0)/B(1) too (older) -- prologue-only cost
#pragma unroll
    for (int i = 0; i < 3; ++i) {
      short4 s;
      s.x = f2b(avP[i].x); s.y = f2b(avP[i].y);
      s.z = f2b(avP[i].z); s.w = f2b(avP[i].w);
      *(short4*)(As + wAo[i]) = s;
    }
  }
#pragma unroll
  for (int i = 0; i < 3; ++i) avA[i] = *(const float4*)(pA[i] + 64);
#pragma unroll
  for (int i = 0; i < 3; ++i) avB[i] = *(const float4*)(pA[i] + 128);
  __builtin_amdgcn_sched_barrier(0);
  asm volatile("s_waitcnt vmcnt(6) lgkmcnt(0)");
  __builtin_amdgcn_sched_barrier(0);
  __builtin_amdgcn_s_barrier();
  __builtin_amdgcn_sched_barrier(0);

  // ---- ITER(kk): DMA B(kk+2)->Bs[DB]; cvt AV=A(kk+1)->As[DA]; load A(kk+3)->AV;
  //      MFMA As[MA] x Bs[MB]; vmcnt(10) drains B(kk+1); barrier.
  //      MB=kk%3, DB=(kk+2)%3, MA=kk&1, DA=(kk+1)&1 -- all literals.
#define ITER(kk, AV, MB, DB, MA, DA)                                                  \
  do {                                                                                \
    _Pragma("unroll")                                                                 \
    for (int i = 0; i < 4; ++i)                                                       \
      load_lds16(pB[i] + ((kk) + 2) * 64, Bs + (DB) * 16384 + dB[i]);                 \
    __builtin_amdgcn_sched_barrier(0);                                                \
    _Pragma("unroll")                                                                 \
    for (int i = 0; i < 3; ++i) {                                                     \
      short4 s;                                                                       \
      s.x = f2b(AV[i].x); s.y = f2b(AV[i].y);                                         \
      s.z = f2b(AV[i].z); s.w = f2b(AV[i].w);                                         \
      *(short4*)(As + (DA) * 6144 + wAo[i]) = s;                                      \
    }                                                                                 \
    {                                                                                 \
      int kn_ = ((kk) + 3) & 31;                                                      \
      _Pragma("unroll")                                                               \
      for (int i = 0; i < 3; ++i) AV[i] = *(const float4*)(pA[i] + kn_ * 64);         \
    }                                                                                 \
    {                                                                                 \
      const __hip_bfloat16* Ab_ = As + (MA) * 6144;                                   \
      const __hip_bfloat16* Bb_ = Bs + (MB) * 16384;                                  \
      _Pragma("unroll")                                                               \
      for (int ks = 0; ks < 2; ++ks) {                                                \
        bhalf8 af[3], bf[4];                                                          \
        _Pragma("unroll")                                                             \
        for (int i = 0; i < 3; ++i) af[i] = *(const bhalf8*)(Ab_ + rAo[ks][i]);       \
        _Pragma("unroll")                                                             \
        for (int j = 0; j < 4; ++j) bf[j] = *(const bhalf8*)(Bb_ + rBo[ks][j]);       \
        _Pragma("unroll")                                                             \
        for (int i = 0; i < 3; ++i)                                                   \
          _Pragma("unroll")                                                           \
          for (int j = 0; j < 4; ++j)                                                 \
            acc[i][j] = __builtin_amdgcn_mfma_f32_16x16x32_bf16(af[i], bf[j],         \
                                                                acc[i][j], 0, 0, 0); \
      }                                                                               \
    }                                                                                 \
    __builtin_amdgcn_sched_barrier(0);                                                \
    asm volatile("s_waitcnt vmcnt(10) lgkmcnt(0)");                                   \
    __builtin_amdgcn_sched_barrier(0);                                                \
    __builtin_amdgcn_s_barrier();                                                     \
    __builtin_amdgcn_sched_barrier(0);                                                \
  } while (0)

  // ---------------- main loop: tiles 0..29; tiles 30,31 in tails ----------------
  for (int k = 0; k < 30; k += 6) {
    ITER(k + 0, avA, 0, 2, 0, 1);
    ITER(k + 1, avB, 1, 0, 1, 0);
    ITER(k + 2, avA, 2, 1, 0, 1);
    ITER(k + 3, avB, 0, 2, 1, 0);
    ITER(k + 4, avA, 1, 0, 0, 1);
    ITER(k + 5, avB, 2, 1, 1, 0);
  }
#undef ITER

  // tail tile 30: cvt A(31) (avA) -> As[1]; MFMA As[0] x Bs[0]; drain B(31)
  {
#pragma unroll
    for (int i = 0; i < 3; ++i) {
      short4 s;
      s.x = f2b(avA[i].x); s.y = f2b(avA[i].y);
      s.z = f2b(avA[i].z); s.w = f2b(avA[i].w);
      *(short4*)(As + 6144 + wAo[i]) = s;
    }
    const __hip_bfloat16* Ab = As;
    const __hip_bfloat16* Bb = Bs;            // buf 0 = tile 30 (30%3==0)
#pragma unroll
    for (int ks = 0; ks < 2; ++ks) {
      bhalf8 af[3], bf[4];
#pragma unroll
      for (int i = 0; i < 3; ++i) af[i] = *(const bhalf8*)(Ab + rAo[ks][i]);
#pragma unroll
      for (int j = 0; j < 4; ++j) bf[j] = *(const bhalf8*)(Bb + rBo[ks][j]);
#pragma unroll
      for (int i = 0; i < 3; ++i)
#pragma unroll
        for (int j = 0; j < 4; ++j)
          acc[i][j] = __builtin_amdgcn_mfma_f32_16x16x32_bf16(af[i], bf[j], acc[i][j], 0, 0, 0);
    }
  }
  __builtin_amdgcn_sched_barrier(0);
  asm volatile("s_waitcnt vmcnt(3) lgkmcnt(0)");   // drain B(31)x4; keep A-reload x3
  __builtin_amdgcn_sched_barrier(0);
  __builtin_amdgcn_s_barrier();
  __builtin_amdgcn_sched_barrier(0);
  // keep the benign A(0) reload (in avB) alive so the vmcnt ledger holds
  asm volatile("" :: "v"(avB[0].x), "v"(avB[1].x), "v"(avB[2].x));

  // tail tile 31: MFMA As[1] x Bs[1]  (B(31) lives in buffer 31%3 == 1)
  {
    const __hip_bfloat16* Ab = As + 6144;
    const __hip_bfloat16* Bb = Bs + 16384;
#pragma unroll
    for (int ks = 0; ks < 2; ++ks) {
      bhalf8 af[3], bf[4];
#pragma unroll
      for (int i = 0; i < 3; ++i) af[i] = *(const bhalf8*)(Ab + rAo[ks][i]);
#pragma unroll
      for (int j = 0; j < 4; ++j) bf[j] = *(const bhalf8*)(Bb + rBo[ks][j]);
#pragma unroll
      for (int i = 0; i < 3; ++i)
#pragma unroll
        for (int j = 0; j < 4; ++j)
          acc[i][j] = __builtin_amdgcn_mfma_f32_16x16x32_bf16(af[i], bf[j], acc[i][j], 0, 0, 0);
    }
  }

  // epilogue: C/D layout col = lane&15, row = q*4 + reg
  float bv[4];
#pragma unroll
  for (int j = 0; j < 4; ++j) bv[j] = bias[e * D_SZ + wn * 64 + j * 16 + l15];

#pragma unroll
  for (int i = 0; i < 3; ++i) {
#pragma unroll
    for (int r = 0; r < 4; ++r) {
      int gm = mbase + wm * 48 + i * 16 + q * 4 + r;
      if (gm < count) {
        int row = permE[gm];
        float* po = out + (size_t)row * D_SZ + wn * 64;
#pragma unroll
        for (int j = 0; j < 4; ++j) po[j * 16 + l15] = acc[i][j][r] + bv[j];
      }
    }
  }
}

extern "C" void kernel_launch(void* const* d_in, const int* in_sizes, int n_in,
                              void* d_out, int out_size, void* d_ws, size_t ws_size,
                              hipStream_t stream) {
  const float* x = (const float*)d_in[0];
  const float* W = (const float*)d_in[1];
  const float* bias = (const float*)d_in[2];
  const int* ids = (const int*)d_in[3];
  float* out = (float*)d_out;

  char* ws = (char*)d_ws;
  int* counts = (int*)ws;                                 // 32 B
  int* perm = (int*)(ws + 256);                           // 512 KB
  __hip_bfloat16* Wt = (__hip_bfloat16*)(ws + (1 << 20)); // 8 MB

  hipMemsetAsync(counts, 0, E_SZ * sizeof(int), stream);
  k_scatter<<<B_SZ / 256, 256, 0, stream>>>(ids, counts, perm);
  k_transpose<<<dim3(F_SZ / 64, D_SZ / 64, E_SZ), 256, 0, stream>>>(W, Wt);
  k_gemm<<<GRID_G, 512, 0, stream>>>(x, Wt, bias, counts, perm, out);
}